// Round 1
// baseline (98.195 us; speedup 1.0000x reference)
//
#include <hip/hip_runtime.h>
#include <hip/hip_bf16.h>
#include <stdint.h>

#define K_DIM 20000
#define N_DIM 512
#define M_DIM 2048

#define BM 128
#define BN 128
#define BK 32
#define PAD 56            // ushorts per LDS row = 112 B: 16B-aligned, 8 distinct bank groups
#define NSTEPS 625        // K_DIM / BK  (exact)
#define SPLITS 8
#define GEMM_THREADS 256

typedef __bf16 bf16_t;
typedef bf16_t  bf16x8 __attribute__((ext_vector_type(8)));
typedef float   f32x4  __attribute__((ext_vector_type(4)));
typedef uint32_t u32x2 __attribute__((ext_vector_type(2)));
typedef uint32_t u32x4 __attribute__((ext_vector_type(4)));

__device__ __forceinline__ uint32_t pack_bf16x2(float a, float b) {
  uint32_t ua = (uint32_t)__builtin_bit_cast(uint16_t, (bf16_t)a);
  uint32_t ub = (uint32_t)__builtin_bit_cast(uint16_t, (bf16_t)b);
  return ua | (ub << 16);
}

// ---------------------------------------------------------------------------
// Kernel 0: E (K x N fp32, row-major) -> Bt (N x K bf16, row-major)
// Tile: 32 k x 64 n per block; 256 threads; each thread: 8 k for one n.
// Reads: per j, 4 k-rows x 16 consecutive n x 4B = 64B segments (coalesced-ish).
// Writes: 4 lanes x 16B = 64B contiguous per n-row.
// ---------------------------------------------------------------------------
__global__ __launch_bounds__(256)
void bt_transpose_kernel(const float* __restrict__ B, uint16_t* __restrict__ Bt) {
  const int kb = blockIdx.x;      // 0..624
  const int nb = blockIdx.y;      // 0..7
  const int t  = threadIdx.x;
  const int rn = t >> 2;          // 0..63 local n
  const int kc = t & 3;           // 0..3  (8 k each)
  const int n  = nb * 64 + rn;
  const int kk = kb * 32 + kc * 8;

  float v[8];
#pragma unroll
  for (int j = 0; j < 8; ++j)
    v[j] = B[(size_t)(kk + j) * N_DIM + n];

  u32x4 q;
#pragma unroll
  for (int j = 0; j < 4; ++j)
    q[j] = pack_bf16x2(v[2 * j], v[2 * j + 1]);

  *reinterpret_cast<u32x4*>(&Bt[(size_t)n * K_DIM + kk]) = q;
}

// ---------------------------------------------------------------------------
// Kernel 1: out[m][n] = bias[n]   (accumulation target for split-K atomics)
// ---------------------------------------------------------------------------
__global__ __launch_bounds__(256)
void init_out_kernel(const float* __restrict__ bias, float* __restrict__ out) {
  const int i = blockIdx.x * 256 + threadIdx.x;
  out[i] = bias[i & (N_DIM - 1)];
}

// ---------------------------------------------------------------------------
// Kernel 2: split-K bf16 MFMA GEMM.
//   C[m][n] += (1/K) * sum_k bf16(x[m][k]) * Bt[n][k]
// 128x128 tile, 4 waves (2x2), each wave 64x64 = 4x4 frags of 16x16x32.
// BK=32, double-buffered LDS; A converted fp32->bf16 during staging.
// grid = 64 tiles * 8 K-splits = 512 blocks, 256 threads.
// ---------------------------------------------------------------------------
__global__ __launch_bounds__(GEMM_THREADS)
void gemm_split_kernel(const float* __restrict__ X,
                       const uint16_t* __restrict__ Bt,
                       float* __restrict__ out) {
  __shared__ __align__(16) uint16_t Al[2][BM][PAD];
  __shared__ __align__(16) uint16_t Bl[2][BN][PAD];

  const int bid  = blockIdx.x;
  const int s    = bid >> 6;       // K-split 0..7
  const int tile = bid & 63;
  const int mt   = tile & 15;
  const int nt   = tile >> 4;      // 0..3
  const int m0 = mt * BM;
  const int n0 = nt * BN;
  const int step0 = (s * NSTEPS) / SPLITS;
  const int step1 = ((s + 1) * NSTEPS) / SPLITS;
  const int nsteps = step1 - step0;   // 78 or 79

  const int t    = threadIdx.x;
  const int wid  = t >> 6;
  const int lane = t & 63;
  const int wr  = (wid >> 1) * 64;  // wave row offset in tile
  const int wc  = (wid & 1) * 64;   // wave col offset in tile
  const int l15 = lane & 15;
  const int l16 = lane >> 4;        // 0..3

  // staging decomposition
  const int arow = t >> 3;          // 0..31 (A: 4 passes of 32 rows)
  const int af4  = t & 7;           // 8 x float4 per 32-float row
  const int brow = t >> 2;          // 0..63 (B: 2 passes of 64 rows)
  const int bu4  = t & 3;           // 4 x 16B per 32-bf16 row

  const float*    __restrict__ xrow  = X  + (size_t)(m0 + arow) * K_DIM;
  const uint16_t* __restrict__ btrow = Bt + (size_t)(n0 + brow) * K_DIM;

  f32x4 acc[4][4] = {};

  // prologue: stage step0 into buffer 0
  {
    const int kpos = step0 * BK;
#pragma unroll
    for (int p = 0; p < 4; ++p) {
      f32x4 v = *reinterpret_cast<const f32x4*>(xrow + (size_t)p * 32 * K_DIM + kpos + af4 * 4);
      u32x2 w;
      w[0] = pack_bf16x2(v[0], v[1]);
      w[1] = pack_bf16x2(v[2], v[3]);
      *reinterpret_cast<u32x2*>(&Al[0][arow + p * 32][af4 * 4]) = w;
    }
#pragma unroll
    for (int p = 0; p < 2; ++p) {
      u32x4 v = *reinterpret_cast<const u32x4*>(btrow + (size_t)p * 64 * K_DIM + kpos + bu4 * 8);
      *reinterpret_cast<u32x4*>(&Bl[0][brow + p * 64][bu4 * 8]) = v;
    }
  }
  __syncthreads();

  int buf = 0;
  for (int i = 0; i < nsteps; ++i) {
    // issue next-step global loads early (land under MFMA)
    f32x4 av[4];
    u32x4 bv[2];
    const bool have = (i + 1 < nsteps);
    if (have) {
      const int kpos = (step0 + i + 1) * BK;
#pragma unroll
      for (int p = 0; p < 4; ++p)
        av[p] = *reinterpret_cast<const f32x4*>(xrow + (size_t)p * 32 * K_DIM + kpos + af4 * 4);
#pragma unroll
      for (int p = 0; p < 2; ++p)
        bv[p] = *reinterpret_cast<const u32x4*>(btrow + (size_t)p * 64 * K_DIM + kpos + bu4 * 8);
    }

    // compute current buffer
    bf16x8 afr[4], bfr[4];
#pragma unroll
    for (int mf = 0; mf < 4; ++mf)
      afr[mf] = *reinterpret_cast<const bf16x8*>(&Al[buf][wr + mf * 16 + l15][l16 * 8]);
#pragma unroll
    for (int nf = 0; nf < 4; ++nf)
      bfr[nf] = *reinterpret_cast<const bf16x8*>(&Bl[buf][wc + nf * 16 + l15][l16 * 8]);
#pragma unroll
    for (int mf = 0; mf < 4; ++mf)
#pragma unroll
      for (int nf = 0; nf < 4; ++nf)
        acc[mf][nf] = __builtin_amdgcn_mfma_f32_16x16x32_bf16(afr[mf], bfr[nf], acc[mf][nf], 0, 0, 0);

    // write next-step tiles into the other buffer
    if (have) {
      const int nbuf = buf ^ 1;
#pragma unroll
      for (int p = 0; p < 4; ++p) {
        u32x2 w;
        w[0] = pack_bf16x2(av[p][0], av[p][1]);
        w[1] = pack_bf16x2(av[p][2], av[p][3]);
        *reinterpret_cast<u32x2*>(&Al[nbuf][arow + p * 32][af4 * 4]) = w;
      }
#pragma unroll
      for (int p = 0; p < 2; ++p)
        *reinterpret_cast<u32x4*>(&Bl[nbuf][brow + p * 64][bu4 * 8]) = bv[p];
    }
    __syncthreads();
    buf ^= 1;
  }

  // epilogue: scaled atomic accumulation (C/D layout: col = lane&15, row = (lane>>4)*4 + j)
  const float scale = 1.0f / (float)K_DIM;
#pragma unroll
  for (int mf = 0; mf < 4; ++mf) {
#pragma unroll
    for (int nf = 0; nf < 4; ++nf) {
      const int row = m0 + wr + mf * 16 + l16 * 4;
      const int col = n0 + wc + nf * 16 + l15;
#pragma unroll
      for (int j = 0; j < 4; ++j)
        atomicAdd(&out[(size_t)(row + j) * N_DIM + col], acc[mf][nf][j] * scale);
    }
  }
}

// ---------------------------------------------------------------------------
extern "C" void kernel_launch(void* const* d_in, const int* in_sizes, int n_in,
                              void* d_out, int out_size, void* d_ws, size_t ws_size,
                              hipStream_t stream) {
  (void)in_sizes; (void)n_in; (void)out_size; (void)ws_size;
  const float* x    = (const float*)d_in[0];
  const float* emb  = (const float*)d_in[1];
  const float* bias = (const float*)d_in[2];
  float*    out = (float*)d_out;
  uint16_t* bt  = (uint16_t*)d_ws;   // 512*20000*2 = 20.48 MB

  bt_transpose_kernel<<<dim3(K_DIM / 32, N_DIM / 64), 256, 0, stream>>>(emb, bt);
  init_out_kernel<<<(M_DIM * N_DIM) / 256, 256, 0, stream>>>(bias, out);
  gemm_split_kernel<<<64 * SPLITS, GEMM_THREADS, 0, stream>>>(x, bt, out);
}